// Round 1
// baseline (5319.020 us; speedup 1.0000x reference)
//
#include <hip/hip_runtime.h>
#include <cstddef>

namespace {

constexpr int B = 64, T = 128, S = 16, H = 512;

// ---------------------------------------------------------------------------
// Whh [4][1024][256] -> WT [4][256][1024]   (so recurrent dot is coalesced)
// ---------------------------------------------------------------------------
__global__ __launch_bounds__(256)
void k_transpose_whh(const float* __restrict__ whh, float* __restrict__ wt) {
  int idx = blockIdx.x * 256 + threadIdx.x;   // 4*1024*256 = 1048576 total
  int ld = idx >> 18;
  int rem = idx & 262143;
  int j = rem >> 10;          // 0..255  (hidden index)
  int row = rem & 1023;       // 0..1023 (gate row)
  wt[idx] = whh[(ld << 18) + row * 256 + j];
}

// ---------------------------------------------------------------------------
// xg[m][n] = X[m] . Wih_l[n] + bih[n] + bhh[n]   m = b*T+t (8192), n (2048)
// 32 rows/block in LDS; each thread owns 2 weight rows, streams them once.
// ---------------------------------------------------------------------------
__global__ __launch_bounds__(256, 2)
void k_xg(const float* __restrict__ X, const float* __restrict__ Wih,
          const float* __restrict__ bih, const float* __restrict__ bhh,
          float* __restrict__ xg, int l) {
  __shared__ __align__(16) float sa[32 * 512];
  int tid = threadIdx.x;
  size_t rowbase = (size_t)blockIdx.x * 32;
  const float4* src = (const float4*)(X + rowbase * 512);
  float4* dst = (float4*)sa;
  for (int idx = tid; idx < 4096; idx += 256) dst[idx] = src[idx];
  __syncthreads();
  const float* W  = Wih + (size_t)l * 2048 * 512;
  const float* bi = bih + l * 2048;
  const float* bh = bhh + l * 2048;
  for (int nc = 0; nc < 4; ++nc) {
    int n0 = nc * 256 + tid;
    int n1 = n0 + 1024;
    float acc0[32], acc1[32];
#pragma unroll
    for (int i = 0; i < 32; ++i) { acc0[i] = 0.f; acc1[i] = 0.f; }
    const float4* wp0 = (const float4*)(W + (size_t)n0 * 512);
    const float4* wp1 = (const float4*)(W + (size_t)n1 * 512);
    for (int k4 = 0; k4 < 128; ++k4) {
      float4 w0 = wp0[k4], w1 = wp1[k4];
#pragma unroll
      for (int i = 0; i < 32; ++i) {
        float4 a = *(const float4*)(sa + i * 512 + 4 * k4);
        acc0[i] += w0.x * a.x + w0.y * a.y + w0.z * a.z + w0.w * a.w;
        acc1[i] += w1.x * a.x + w1.y * a.y + w1.z * a.z + w1.w * a.w;
      }
    }
    float bb0 = bi[n0] + bh[n0];
    float bb1 = bi[n1] + bh[n1];
#pragma unroll
    for (int i = 0; i < 32; ++i) {
      xg[(rowbase + i) * 2048 + n0] = acc0[i] + bb0;
      xg[(rowbase + i) * 2048 + n1] = acc1[i] + bb1;
    }
  }
}

// ---------------------------------------------------------------------------
// Masked LSTM recurrence, one (batch-pair, direction) per block.
// xg already holds x@Wih^T + bih + bhh. Gate order i,f,g,o.
// ---------------------------------------------------------------------------
__global__ __launch_bounds__(256)
void k_lstm(const float* __restrict__ xg, const float* __restrict__ wt,
            const int* __restrict__ lens, float* __restrict__ out, int l) {
  int d  = blockIdx.x >> 5;
  int bp = blockIdx.x & 31;
  int b0 = bp * 2, b1 = b0 + 1;
  int k = threadIdx.x;
  const float* w = wt + (size_t)(l * 2 + d) * 262144;   // [256][1024]
  __shared__ float hb[2][256];
  float h0 = 0.f, c0 = 0.f, h1 = 0.f, c1 = 0.f;
  int len0 = lens[b0], len1 = lens[b1];
  for (int s = 0; s < T; ++s) {
    int t = d ? (T - 1 - s) : s;
    hb[0][k] = h0; hb[1][k] = h1;
    __syncthreads();
    const float* x0 = xg + ((size_t)b0 * T + t) * 2048 + d * 1024;
    const float* x1 = xg + ((size_t)b1 * T + t) * 2048 + d * 1024;
    float a00 = x0[k],       a01 = x1[k];
    float a10 = x0[256 + k], a11 = x1[256 + k];
    float a20 = x0[512 + k], a21 = x1[512 + k];
    float a30 = x0[768 + k], a31 = x1[768 + k];
#pragma unroll 4
    for (int j = 0; j < 256; ++j) {
      const float* wj = w + j * 1024 + k;
      float w0 = wj[0], w1 = wj[256], w2 = wj[512], w3 = wj[768];
      float hj0 = hb[0][j], hj1 = hb[1][j];
      a00 += w0 * hj0; a01 += w0 * hj1;
      a10 += w1 * hj0; a11 += w1 * hj1;
      a20 += w2 * hj0; a21 += w2 * hj1;
      a30 += w3 * hj0; a31 += w3 * hj1;
    }
    {
      float ig = 1.f / (1.f + expf(-a00));
      float fg = 1.f / (1.f + expf(-a10));
      float gg = tanhf(a20);
      float og = 1.f / (1.f + expf(-a30));
      float c2 = fg * c0 + ig * gg;
      float h2 = og * tanhf(c2);
      if (t < len0) { c0 = c2; h0 = h2; }
      out[((size_t)b0 * T + t) * 512 + d * 256 + k] = h0;
    }
    {
      float ig = 1.f / (1.f + expf(-a01));
      float fg = 1.f / (1.f + expf(-a11));
      float gg = tanhf(a21);
      float og = 1.f / (1.f + expf(-a31));
      float c2 = fg * c1 + ig * gg;
      float h2 = og * tanhf(c2);
      if (t < len1) { c1 = c2; h1 = h2; }
      out[((size_t)b1 * T + t) * 512 + d * 256 + k] = h1;
    }
    __syncthreads();
  }
}

// ---------------------------------------------------------------------------
// sc[m] = w2 . tanh(W1 @ rnn[m] + b1)   per (b,t) row; 32 rows/block
// ---------------------------------------------------------------------------
__global__ __launch_bounds__(256)
void k_attn_sc(const float* __restrict__ rnn, const float* __restrict__ W1,
               const float* __restrict__ b1, const float* __restrict__ w2,
               float* __restrict__ sc) {
  __shared__ __align__(16) float sa[32 * 512];
  __shared__ float shred[4][32];
  int tid = threadIdx.x;
  int rowbase = blockIdx.x * 32;
  const float4* src = (const float4*)(rnn + (size_t)rowbase * 512);
  float4* dst = (float4*)sa;
  for (int idx = tid; idx < 4096; idx += 256) dst[idx] = src[idx];
  __syncthreads();
  float spart[32];
#pragma unroll
  for (int i = 0; i < 32; ++i) spart[i] = 0.f;
  for (int nc = 0; nc < 2; ++nc) {
    int n = nc * 256 + tid;
    float acc[32];
#pragma unroll
    for (int i = 0; i < 32; ++i) acc[i] = 0.f;
    const float4* wp = (const float4*)(W1 + (size_t)n * 512);
    for (int k4 = 0; k4 < 128; ++k4) {
      float4 w = wp[k4];
#pragma unroll
      for (int i = 0; i < 32; ++i) {
        float4 a = *(const float4*)(sa + i * 512 + 4 * k4);
        acc[i] += w.x * a.x + w.y * a.y + w.z * a.z + w.w * a.w;
      }
    }
    float bn = b1[n], wn = w2[n];
#pragma unroll
    for (int i = 0; i < 32; ++i) spart[i] += wn * tanhf(acc[i] + bn);
  }
  int lane = tid & 63, wv = tid >> 6;
#pragma unroll
  for (int i = 0; i < 32; ++i) {
    float v = spart[i];
    v += __shfl_xor(v, 32);
    v += __shfl_xor(v, 16);
    v += __shfl_xor(v, 8);
    v += __shfl_xor(v, 4);
    v += __shfl_xor(v, 2);
    v += __shfl_xor(v, 1);
    if (lane == 0) shred[wv][i] = v;
  }
  __syncthreads();
  if (tid < 32)
    sc[rowbase + tid] = shred[0][tid] + shred[1][tid] + shred[2][tid] + shred[3][tid];
}

// ---------------------------------------------------------------------------
// Causal softmax + weighted sum as a prefix scan:
// ctx[b,t] = sum_{s<=t} e^{sc_s} rnn_s / sum_{s<=t} e^{sc_s}; 0 for t >= len
// ---------------------------------------------------------------------------
__global__ __launch_bounds__(512)
void k_ctx(const float* __restrict__ sc, const float* __restrict__ rnn,
           const int* __restrict__ lens, float* __restrict__ ctx) {
  int b = blockIdx.x;
  int h = threadIdx.x;
  __shared__ float ex[T];
  if (h < T) ex[h] = expf(sc[b * T + h]);
  __syncthreads();
  int len = lens[b];
  float acc = 0.f, den = 0.f;
  for (int t = 0; t < T; ++t) {
    float wv = ex[t];
    den += wv;
    acc += wv * rnn[((size_t)b * T + t) * 512 + h];
    ctx[((size_t)b * T + t) * 512 + h] = (t < len) ? (acc / den) : 0.f;
  }
}

// ---------------------------------------------------------------------------
// One fused MLP stage on a 32-row LDS tile: O = act(A @ W^T + b)
// thread owns weight row n = tid%N, processes 32/(256/N) rows; A reads are
// wave-uniform (broadcast), W rows streamed once per block.
// ---------------------------------------------------------------------------
template <int N, int K, int LDA, int LDO, bool RELU>
__device__ __forceinline__ void mlp_stage(const float* __restrict__ W,
                                          const float* __restrict__ bias,
                                          const float* A, float* O, int tid) {
  constexpr int NTHR = 256 / N;
  constexpr int ROWS = 32 / NTHR;
  static_assert(ROWS * NTHR == 32, "");
  int n = tid % N;
  int r0 = (tid / N) * ROWS;
  float acc[ROWS];
#pragma unroll
  for (int i = 0; i < ROWS; ++i) acc[i] = 0.f;
  const float4* wp = (const float4*)(W + (size_t)n * K);
  for (int k4 = 0; k4 < K / 4; ++k4) {
    float4 w = wp[k4];
#pragma unroll
    for (int i = 0; i < ROWS; ++i) {
      float4 a = *(const float4*)(A + (r0 + i) * LDA + 4 * k4);
      acc[i] += w.x * a.x + w.y * a.y + w.z * a.z + w.w * a.w;
    }
  }
  float bv = bias[n];
#pragma unroll
  for (int i = 0; i < ROWS; ++i) {
    float v = acc[i] + bv;
    O[(r0 + i) * LDO + n] = RELU ? fmaxf(v, 0.f) : v;
  }
}

// ---------------------------------------------------------------------------
// Fully fused sample branch: e-MLP, r-branch, lm chain, sigmoid. 32 rows/blk.
// row m = (b*T+t)*S + s
// ---------------------------------------------------------------------------
__global__ __launch_bounds__(256)
void k_sample(const float* __restrict__ ctx, const float* __restrict__ d2v,
              const float* __restrict__ user_table, const float* __restrict__ art_table,
              const int* __restrict__ user_ids, const int* __restrict__ sample_ids,
              const float* __restrict__ em_W1, const float* __restrict__ em_b1,
              const float* __restrict__ em_W2, const float* __restrict__ em_b2,
              const float* __restrict__ mlp_W, const float* __restrict__ mlp_b,
              const float* __restrict__ lm_W1, const float* __restrict__ lm_b1,
              const float* __restrict__ lm_W2, const float* __restrict__ lm_b2,
              const float* __restrict__ lm_W3, const float* __restrict__ lm_b3,
              const float* __restrict__ lm_W4, const float* __restrict__ lm_b4,
              float* __restrict__ out) {
  __shared__ __align__(16) float shx[32 * 128];
  __shared__ __align__(16) float shy[32 * 256];
  __shared__ __align__(16) float shz[32 * 128];
  int tid = threadIdx.x;
  int rowbase = blockIdx.x * 32;

  // e0 = user_emb * art_emb
  for (int idx = tid; idx < 1024; idx += 256) {
    int r = idx >> 5, k4 = idx & 31;
    int m = rowbase + r;
    int b = m >> 11;                         // m / (T*S)
    int sid = sample_ids[m];
    int uid = user_ids[b];
    float4 u = *(const float4*)(user_table + (size_t)uid * 128 + k4 * 4);
    float4 a = *(const float4*)(art_table + (size_t)sid * 128 + k4 * 4);
    *(float4*)(shx + r * 128 + k4 * 4) =
        make_float4(u.x * a.x, u.y * a.y, u.z * a.z, u.w * a.w);
  }
  __syncthreads();
  mlp_stage<128, 128, 128, 256, true>(em_W1, em_b1, shx, shy, tid);  // e1 -> shy
  __syncthreads();
  mlp_stage<64, 128, 256, 128, true>(em_W2, em_b2, shy, shz, tid);   // e2 -> shz[:, :64]
  __syncthreads();

  // r branch: r = (ctx * d2v) @ mlp_W^T + mlp_b  (K=512 in 4 chunks)
  {
    int n = tid & 63, r0 = (tid >> 6) * 8;
    float racc[8];
#pragma unroll
    for (int i = 0; i < 8; ++i) racc[i] = 0.f;
    for (int kc = 0; kc < 4; ++kc) {
      for (int idx = tid; idx < 1024; idx += 256) {
        int r = idx >> 5, k4 = idx & 31;
        int m = rowbase + r;
        int bt = m >> 4;
        float4 c = *(const float4*)(ctx + (size_t)bt * 512 + kc * 128 + k4 * 4);
        float4 dv = *(const float4*)(d2v + (size_t)m * 512 + kc * 128 + k4 * 4);
        *(float4*)(shx + r * 128 + k4 * 4) =
            make_float4(c.x * dv.x, c.y * dv.y, c.z * dv.z, c.w * dv.w);
      }
      __syncthreads();
      const float4* wp = (const float4*)(mlp_W + (size_t)n * 512 + kc * 128);
      for (int k4 = 0; k4 < 32; ++k4) {
        float4 w = wp[k4];
#pragma unroll
        for (int i = 0; i < 8; ++i) {
          float4 a = *(const float4*)(shx + (r0 + i) * 128 + k4 * 4);
          racc[i] += w.x * a.x + w.y * a.y + w.z * a.z + w.w * a.w;
        }
      }
      __syncthreads();
    }
    float bv = mlp_b[n];
#pragma unroll
    for (int i = 0; i < 8; ++i) shz[(r0 + i) * 128 + 64 + n] = racc[i] + bv;
  }
  __syncthreads();

  mlp_stage<256, 128, 128, 256, true>(lm_W1, lm_b1, shz, shy, tid);  // z1 -> shy
  __syncthreads();
  mlp_stage<128, 256, 256, 128, true>(lm_W2, lm_b2, shy, shx, tid);  // z2 -> shx
  __syncthreads();
  mlp_stage<64, 128, 128, 128, true>(lm_W3, lm_b3, shx, shz, tid);   // z3 -> shz[:, :64]
  __syncthreads();

  if (tid < 32) {
    float acc = lm_b4[0];
#pragma unroll
    for (int k = 0; k < 64; ++k) acc += shz[tid * 128 + k] * lm_W4[k];
    out[rowbase + tid] = 1.f / (1.f + expf(-acc));
  }
}

}  // namespace

extern "C" void kernel_launch(void* const* d_in, const int* in_sizes, int n_in,
                              void* d_out, int out_size, void* d_ws, size_t ws_size,
                              hipStream_t stream) {
  const float* x1   = (const float*)d_in[0];
  const float* d2v  = (const float*)d_in[1];
  const float* Wih  = (const float*)d_in[2];
  const float* Whh  = (const float*)d_in[3];
  const float* bih  = (const float*)d_in[4];
  const float* bhh  = (const float*)d_in[5];
  const float* aW1  = (const float*)d_in[6];
  const float* ab1  = (const float*)d_in[7];
  const float* aw2  = (const float*)d_in[8];
  const float* mlpW = (const float*)d_in[9];
  const float* mlpb = (const float*)d_in[10];
  const float* utab = (const float*)d_in[11];
  const float* atab = (const float*)d_in[12];
  const float* emW1 = (const float*)d_in[13];
  const float* emb1 = (const float*)d_in[14];
  const float* emW2 = (const float*)d_in[15];
  const float* emb2 = (const float*)d_in[16];
  const float* lmW1 = (const float*)d_in[17];
  const float* lmb1 = (const float*)d_in[18];
  const float* lmW2 = (const float*)d_in[19];
  const float* lmb2 = (const float*)d_in[20];
  const float* lmW3 = (const float*)d_in[21];
  const float* lmb3 = (const float*)d_in[22];
  const float* lmW4 = (const float*)d_in[23];
  const float* lmb4 = (const float*)d_in[24];
  const int* lens   = (const int*)d_in[27];
  const int* uids   = (const int*)d_in[28];
  const int* sids   = (const int*)d_in[29];
  float* out = (float*)d_out;

  float* ws = (float*)d_ws;
  float* WT  = ws;               // 1,048,576 f32 (4 MB)
  float* XG  = ws + 1048576;     // 16,777,216 (67 MB)
  float* R0  = ws + 17825792;    // 4,194,304
  float* R1  = ws + 22020096;    // 4,194,304
  float* CTX = ws + 26214400;    // 4,194,304
  float* SC  = ws + 30408704;    // 8,192   (total ~122 MB)

  k_transpose_whh<<<4096, 256, 0, stream>>>(Whh, WT);
  k_xg<<<256, 256, 0, stream>>>(x1, Wih, bih, bhh, XG, 0);
  k_lstm<<<64, 256, 0, stream>>>(XG, WT, lens, R0, 0);
  k_xg<<<256, 256, 0, stream>>>(R0, Wih, bih, bhh, XG, 1);
  k_lstm<<<64, 256, 0, stream>>>(XG, WT, lens, R1, 1);
  k_attn_sc<<<256, 256, 0, stream>>>(R1, aW1, ab1, aw2, SC);
  k_ctx<<<64, 512, 0, stream>>>(SC, R1, lens, CTX);
  k_sample<<<4096, 256, 0, stream>>>(CTX, d2v, utab, atab, uids, sids,
                                     emW1, emb1, emW2, emb2, mlpW, mlpb,
                                     lmW1, lmb1, lmW2, lmb2, lmW3, lmb3,
                                     lmW4, lmb4, out);
}

// Round 2
// 3634.248 us; speedup vs baseline: 1.4636x; 1.4636x over previous
//
#include <hip/hip_runtime.h>
#include <cstddef>

namespace {

constexpr int B = 64, T = 128, S = 16, H = 512;

typedef __attribute__((ext_vector_type(8))) short short8;
typedef __attribute__((ext_vector_type(4))) float f32x4;

__device__ __forceinline__ unsigned short f2bf(float x) {
  unsigned u = __float_as_uint(x);
  u = (u + 0x7FFFu + ((u >> 16) & 1u)) >> 16;
  return (unsigned short)u;
}

__device__ __forceinline__ float sigf(float x) {
  x = fminf(fmaxf(x, -30.f), 30.f);
  return 1.f / (1.f + __expf(-x));
}
__device__ __forceinline__ float tanhfast(float x) {
  float ax = fminf(fabsf(x), 15.f);
  float e = __expf(-2.f * ax);
  float t = (1.f - e) / (1.f + e);
  return x < 0.f ? -t : t;
}

// ---------------------------------------------------------------------------
// xg[m][n] = X[m] . Wih_l[n] + bih[n] + bhh[n]   m = b*T+t (8192), n (2048)
// ---------------------------------------------------------------------------
__global__ __launch_bounds__(256, 2)
void k_xg(const float* __restrict__ X, const float* __restrict__ Wih,
          const float* __restrict__ bih, const float* __restrict__ bhh,
          float* __restrict__ xg, int l) {
  __shared__ __align__(16) float sa[32 * 512];
  int tid = threadIdx.x;
  size_t rowbase = (size_t)blockIdx.x * 32;
  const float4* src = (const float4*)(X + rowbase * 512);
  float4* dst = (float4*)sa;
  for (int idx = tid; idx < 4096; idx += 256) dst[idx] = src[idx];
  __syncthreads();
  const float* W  = Wih + (size_t)l * 2048 * 512;
  const float* bi = bih + l * 2048;
  const float* bh = bhh + l * 2048;
  for (int nc = 0; nc < 4; ++nc) {
    int n0 = nc * 256 + tid;
    int n1 = n0 + 1024;
    float acc0[32], acc1[32];
#pragma unroll
    for (int i = 0; i < 32; ++i) { acc0[i] = 0.f; acc1[i] = 0.f; }
    const float4* wp0 = (const float4*)(W + (size_t)n0 * 512);
    const float4* wp1 = (const float4*)(W + (size_t)n1 * 512);
    for (int k4 = 0; k4 < 128; ++k4) {
      float4 w0 = wp0[k4], w1 = wp1[k4];
#pragma unroll
      for (int i = 0; i < 32; ++i) {
        float4 a = *(const float4*)(sa + i * 512 + 4 * k4);
        acc0[i] += w0.x * a.x + w0.y * a.y + w0.z * a.z + w0.w * a.w;
        acc1[i] += w1.x * a.x + w1.y * a.y + w1.z * a.z + w1.w * a.w;
      }
    }
    float bb0 = bi[n0] + bh[n0];
    float bb1 = bi[n1] + bh[n1];
#pragma unroll
    for (int i = 0; i < 32; ++i) {
      xg[(rowbase + i) * 2048 + n0] = acc0[i] + bb0;
      xg[(rowbase + i) * 2048 + n1] = acc1[i] + bb1;
    }
  }
}

// ---------------------------------------------------------------------------
// MFMA LSTM step kernel: 16 blocks = [d:2][chunk c:8 of 32 hidden].
// Whh chunk (128 gate-rows x 256) held in registers as bf16 MFMA B-frags.
// Per step: gates[64 batch][128] = h_prev @ Wchunk^T via mfma, + xg, act,
// h exchanged via global bf16 buffer with device-scope 16-block barrier.
// mfma_f32_16x16x32_bf16 layouts: A[m=lane%16][k=(lane/16)*8+f],
// B[k=(lane/16)*8+f][n=lane%16], D[m=(lane/16)*4+r][n=lane%16].
// ---------------------------------------------------------------------------
__global__ __launch_bounds__(256, 1)
void k_lstm_mfma(const float* __restrict__ xg, const float* __restrict__ whh,
                 const int* __restrict__ lens, float* __restrict__ out,
                 unsigned short* __restrict__ hg, unsigned* __restrict__ cnt,
                 int layer) {
  const int d = blockIdx.x >> 3, c = blockIdx.x & 7;
  const int tid = threadIdx.x;
  const int w = tid >> 6, l = tid & 63;
  const int lrow = l & 15, lhi = l >> 4;

  // ---- one-time: load weight chunk into B fragments (bf16, registers) ----
  short8 Bf[8][8];
  const float* wbase = whh + (size_t)(layer * 2 + d) * 262144;
#pragma unroll
  for (int kk = 0; kk < 8; ++kk) {
#pragma unroll
    for (int nt = 0; nt < 8; ++nt) {
      int g = nt >> 1;
      int nl = (nt & 1) * 16 + lrow;
      const float* rp = wbase + (size_t)(g * 256 + c * 32 + nl) * 256 + kk * 32 + lhi * 8;
      float4 lo = *(const float4*)rp;
      float4 hi = *(const float4*)(rp + 4);
      short8 b;
      b[0] = (short)f2bf(lo.x); b[1] = (short)f2bf(lo.y);
      b[2] = (short)f2bf(lo.z); b[3] = (short)f2bf(lo.w);
      b[4] = (short)f2bf(hi.x); b[5] = (short)f2bf(hi.y);
      b[6] = (short)f2bf(hi.z); b[7] = (short)f2bf(hi.w);
      Bf[kk][nt] = b;
    }
  }

  const int mb = w * 16 + lhi * 4;   // D-row base (batch)
  int mlen[4];
#pragma unroll
  for (int r = 0; r < 4; ++r) mlen[r] = lens[mb + r];

  float cst[2][4], hst[2][4];
#pragma unroll
  for (int hx = 0; hx < 2; ++hx)
#pragma unroll
    for (int r = 0; r < 4; ++r) { cst[hx][r] = 0.f; hst[hx][r] = 0.f; }

  for (int s = 0; s < 128; ++s) {
    const int t = d ? (127 - s) : s;

    // prefetch xg gate pre-activations (independent of h -> overlaps MFMA)
    float xv[8][4];
#pragma unroll
    for (int nt = 0; nt < 8; ++nt) {
      int nglob = d * 1024 + (nt >> 1) * 256 + c * 32 + (nt & 1) * 16 + lrow;
#pragma unroll
      for (int r = 0; r < 4; ++r)
        xv[nt][r] = xg[((size_t)(mb + r) * 128 + t) * 2048 + nglob];
    }

    f32x4 acc[8];
#pragma unroll
    for (int nt = 0; nt < 8; ++nt) acc[nt] = f32x4{0.f, 0.f, 0.f, 0.f};

    if (s > 0) {
      const short8* ap = (const short8*)(hg + (((d << 1) | (s & 1)) << 14));
#pragma unroll
      for (int kk = 0; kk < 8; ++kk) {
        short8 a = ap[(kk * 4 + lhi) * 64 + w * 16 + lrow];
#pragma unroll
        for (int nt = 0; nt < 8; ++nt)
          acc[nt] = __builtin_amdgcn_mfma_f32_16x16x32_bf16(a, Bf[kk][nt], acc[nt], 0, 0, 0);
      }
    }

    unsigned short* hw = hg + (((d << 1) | ((s & 1) ^ 1)) << 14);
#pragma unroll
    for (int hx = 0; hx < 2; ++hx) {
#pragma unroll
      for (int r = 0; r < 4; ++r) {
        float gi = acc[0 + hx][r] + xv[0 + hx][r];
        float gf = acc[2 + hx][r] + xv[2 + hx][r];
        float gg = acc[4 + hx][r] + xv[4 + hx][r];
        float go = acc[6 + hx][r] + xv[6 + hx][r];
        float c2 = sigf(gf) * cst[hx][r] + sigf(gi) * tanhfast(gg);
        float h2 = sigf(go) * tanhfast(c2);
        bool upd = t < mlen[r];
        cst[hx][r] = upd ? c2 : cst[hx][r];
        float hn = upd ? h2 : hst[hx][r];
        hst[hx][r] = hn;
        int m = mb + r;
        int j = c * 32 + hx * 16 + lrow;
        out[((size_t)m * 128 + t) * 512 + d * 256 + j] = hn;
        hw[((c * 4 + hx * 2 + (lrow >> 3)) * 64 + m) * 8 + (lrow & 7)] = f2bf(hn);
      }
    }

    if (s < 127) {
      __syncthreads();
      if (tid == 0) {
        __threadfence();                    // release: publish h stores (L2 wb)
        atomicAdd(cnt, 1u);                 // device-scope arrive
        unsigned target = 16u * (unsigned)(s + 1);
        while (__hip_atomic_load(cnt, __ATOMIC_RELAXED, __HIP_MEMORY_SCOPE_AGENT) < target)
          __builtin_amdgcn_s_sleep(1);
        __threadfence();                    // acquire: invalidate stale caches
      }
      __syncthreads();
    }
  }
}

// ---------------------------------------------------------------------------
// sc[m] = w2 . tanh(W1 @ rnn[m] + b1)   per (b,t) row; 32 rows/block
// ---------------------------------------------------------------------------
__global__ __launch_bounds__(256)
void k_attn_sc(const float* __restrict__ rnn, const float* __restrict__ W1,
               const float* __restrict__ b1, const float* __restrict__ w2,
               float* __restrict__ sc) {
  __shared__ __align__(16) float sa[32 * 512];
  __shared__ float shred[4][32];
  int tid = threadIdx.x;
  int rowbase = blockIdx.x * 32;
  const float4* src = (const float4*)(rnn + (size_t)rowbase * 512);
  float4* dst = (float4*)sa;
  for (int idx = tid; idx < 4096; idx += 256) dst[idx] = src[idx];
  __syncthreads();
  float spart[32];
#pragma unroll
  for (int i = 0; i < 32; ++i) spart[i] = 0.f;
  for (int nc = 0; nc < 2; ++nc) {
    int n = nc * 256 + tid;
    float acc[32];
#pragma unroll
    for (int i = 0; i < 32; ++i) acc[i] = 0.f;
    const float4* wp = (const float4*)(W1 + (size_t)n * 512);
    for (int k4 = 0; k4 < 128; ++k4) {
      float4 w = wp[k4];
#pragma unroll
      for (int i = 0; i < 32; ++i) {
        float4 a = *(const float4*)(sa + i * 512 + 4 * k4);
        acc[i] += w.x * a.x + w.y * a.y + w.z * a.z + w.w * a.w;
      }
    }
    float bn = b1[n], wn = w2[n];
#pragma unroll
    for (int i = 0; i < 32; ++i) spart[i] += wn * tanhf(acc[i] + bn);
  }
  int lane = tid & 63, wv = tid >> 6;
#pragma unroll
  for (int i = 0; i < 32; ++i) {
    float v = spart[i];
    v += __shfl_xor(v, 32);
    v += __shfl_xor(v, 16);
    v += __shfl_xor(v, 8);
    v += __shfl_xor(v, 4);
    v += __shfl_xor(v, 2);
    v += __shfl_xor(v, 1);
    if (lane == 0) shred[wv][i] = v;
  }
  __syncthreads();
  if (tid < 32)
    sc[rowbase + tid] = shred[0][tid] + shred[1][tid] + shred[2][tid] + shred[3][tid];
}

// ---------------------------------------------------------------------------
// Causal softmax + weighted sum as a prefix scan
// ---------------------------------------------------------------------------
__global__ __launch_bounds__(512)
void k_ctx(const float* __restrict__ sc, const float* __restrict__ rnn,
           const int* __restrict__ lens, float* __restrict__ ctx) {
  int b = blockIdx.x;
  int h = threadIdx.x;
  __shared__ float ex[T];
  if (h < T) ex[h] = expf(sc[b * T + h]);
  __syncthreads();
  int len = lens[b];
  float acc = 0.f, den = 0.f;
  for (int t = 0; t < T; ++t) {
    float wv = ex[t];
    den += wv;
    acc += wv * rnn[((size_t)b * T + t) * 512 + h];
    ctx[((size_t)b * T + t) * 512 + h] = (t < len) ? (acc / den) : 0.f;
  }
}

// ---------------------------------------------------------------------------
// One fused MLP stage on a 32-row LDS tile: O = act(A @ W^T + b)
// ---------------------------------------------------------------------------
template <int N, int K, int LDA, int LDO, bool RELU>
__device__ __forceinline__ void mlp_stage(const float* __restrict__ W,
                                          const float* __restrict__ bias,
                                          const float* A, float* O, int tid) {
  constexpr int NTHR = 256 / N;
  constexpr int ROWS = 32 / NTHR;
  static_assert(ROWS * NTHR == 32, "");
  int n = tid % N;
  int r0 = (tid / N) * ROWS;
  float acc[ROWS];
#pragma unroll
  for (int i = 0; i < ROWS; ++i) acc[i] = 0.f;
  const float4* wp = (const float4*)(W + (size_t)n * K);
  for (int k4 = 0; k4 < K / 4; ++k4) {
    float4 w = wp[k4];
#pragma unroll
    for (int i = 0; i < ROWS; ++i) {
      float4 a = *(const float4*)(A + (r0 + i) * LDA + 4 * k4);
      acc[i] += w.x * a.x + w.y * a.y + w.z * a.z + w.w * a.w;
    }
  }
  float bv = bias[n];
#pragma unroll
  for (int i = 0; i < ROWS; ++i) {
    float v = acc[i] + bv;
    O[(r0 + i) * LDO + n] = RELU ? fmaxf(v, 0.f) : v;
  }
}

// ---------------------------------------------------------------------------
// Fully fused sample branch
// ---------------------------------------------------------------------------
__global__ __launch_bounds__(256)
void k_sample(const float* __restrict__ ctx, const float* __restrict__ d2v,
              const float* __restrict__ user_table, const float* __restrict__ art_table,
              const int* __restrict__ user_ids, const int* __restrict__ sample_ids,
              const float* __restrict__ em_W1, const float* __restrict__ em_b1,
              const float* __restrict__ em_W2, const float* __restrict__ em_b2,
              const float* __restrict__ mlp_W, const float* __restrict__ mlp_b,
              const float* __restrict__ lm_W1, const float* __restrict__ lm_b1,
              const float* __restrict__ lm_W2, const float* __restrict__ lm_b2,
              const float* __restrict__ lm_W3, const float* __restrict__ lm_b3,
              const float* __restrict__ lm_W4, const float* __restrict__ lm_b4,
              float* __restrict__ out) {
  __shared__ __align__(16) float shx[32 * 128];
  __shared__ __align__(16) float shy[32 * 256];
  __shared__ __align__(16) float shz[32 * 128];
  int tid = threadIdx.x;
  int rowbase = blockIdx.x * 32;

  for (int idx = tid; idx < 1024; idx += 256) {
    int r = idx >> 5, k4 = idx & 31;
    int m = rowbase + r;
    int b = m >> 11;
    int sid = sample_ids[m];
    int uid = user_ids[b];
    float4 u = *(const float4*)(user_table + (size_t)uid * 128 + k4 * 4);
    float4 a = *(const float4*)(art_table + (size_t)sid * 128 + k4 * 4);
    *(float4*)(shx + r * 128 + k4 * 4) =
        make_float4(u.x * a.x, u.y * a.y, u.z * a.z, u.w * a.w);
  }
  __syncthreads();
  mlp_stage<128, 128, 128, 256, true>(em_W1, em_b1, shx, shy, tid);
  __syncthreads();
  mlp_stage<64, 128, 256, 128, true>(em_W2, em_b2, shy, shz, tid);
  __syncthreads();

  {
    int n = tid & 63, r0 = (tid >> 6) * 8;
    float racc[8];
#pragma unroll
    for (int i = 0; i < 8; ++i) racc[i] = 0.f;
    for (int kc = 0; kc < 4; ++kc) {
      for (int idx = tid; idx < 1024; idx += 256) {
        int r = idx >> 5, k4 = idx & 31;
        int m = rowbase + r;
        int bt = m >> 4;
        float4 cx = *(const float4*)(ctx + (size_t)bt * 512 + kc * 128 + k4 * 4);
        float4 dv = *(const float4*)(d2v + (size_t)m * 512 + kc * 128 + k4 * 4);
        *(float4*)(shx + r * 128 + k4 * 4) =
            make_float4(cx.x * dv.x, cx.y * dv.y, cx.z * dv.z, cx.w * dv.w);
      }
      __syncthreads();
      const float4* wp = (const float4*)(mlp_W + (size_t)n * 512 + kc * 128);
      for (int k4 = 0; k4 < 32; ++k4) {
        float4 w = wp[k4];
#pragma unroll
        for (int i = 0; i < 8; ++i) {
          float4 a = *(const float4*)(shx + (r0 + i) * 128 + k4 * 4);
          racc[i] += w.x * a.x + w.y * a.y + w.z * a.z + w.w * a.w;
        }
      }
      __syncthreads();
    }
    float bv = mlp_b[n];
#pragma unroll
    for (int i = 0; i < 8; ++i) shz[(r0 + i) * 128 + 64 + n] = racc[i] + bv;
  }
  __syncthreads();

  mlp_stage<256, 128, 128, 256, true>(lm_W1, lm_b1, shz, shy, tid);
  __syncthreads();
  mlp_stage<128, 256, 256, 128, true>(lm_W2, lm_b2, shy, shx, tid);
  __syncthreads();
  mlp_stage<64, 128, 128, 128, true>(lm_W3, lm_b3, shx, shz, tid);
  __syncthreads();

  if (tid < 32) {
    float acc = lm_b4[0];
#pragma unroll
    for (int k = 0; k < 64; ++k) acc += shz[tid * 128 + k] * lm_W4[k];
    out[rowbase + tid] = 1.f / (1.f + expf(-acc));
  }
}

}  // namespace

extern "C" void kernel_launch(void* const* d_in, const int* in_sizes, int n_in,
                              void* d_out, int out_size, void* d_ws, size_t ws_size,
                              hipStream_t stream) {
  const float* x1   = (const float*)d_in[0];
  const float* d2v  = (const float*)d_in[1];
  const float* Wih  = (const float*)d_in[2];
  const float* Whh  = (const float*)d_in[3];
  const float* bih  = (const float*)d_in[4];
  const float* bhh  = (const float*)d_in[5];
  const float* aW1  = (const float*)d_in[6];
  const float* ab1  = (const float*)d_in[7];
  const float* aw2  = (const float*)d_in[8];
  const float* mlpW = (const float*)d_in[9];
  const float* mlpb = (const float*)d_in[10];
  const float* utab = (const float*)d_in[11];
  const float* atab = (const float*)d_in[12];
  const float* emW1 = (const float*)d_in[13];
  const float* emb1 = (const float*)d_in[14];
  const float* emW2 = (const float*)d_in[15];
  const float* emb2 = (const float*)d_in[16];
  const float* lmW1 = (const float*)d_in[17];
  const float* lmb1 = (const float*)d_in[18];
  const float* lmW2 = (const float*)d_in[19];
  const float* lmb2 = (const float*)d_in[20];
  const float* lmW3 = (const float*)d_in[21];
  const float* lmb3 = (const float*)d_in[22];
  const float* lmW4 = (const float*)d_in[23];
  const float* lmb4 = (const float*)d_in[24];
  const int* lens   = (const int*)d_in[27];
  const int* uids   = (const int*)d_in[28];
  const int* sids   = (const int*)d_in[29];
  float* out = (float*)d_out;

  float* ws = (float*)d_ws;
  unsigned* CNT      = (unsigned*)ws;                    // 2 counters
  unsigned short* HG = (unsigned short*)(ws + 64);       // 2d x 2p x 32x64x8 bf16
  float* XG  = ws + 1048576;     // 16,777,216 f32
  float* R0  = ws + 17825792;    // 4,194,304
  float* R1  = ws + 22020096;    // 4,194,304
  float* CTX = ws + 26214400;    // 4,194,304
  float* SC  = ws + 30408704;    // 8,192

  hipMemsetAsync(CNT, 0, 8, stream);
  k_xg<<<256, 256, 0, stream>>>(x1, Wih, bih, bhh, XG, 0);
  k_lstm_mfma<<<16, 256, 0, stream>>>(XG, Whh, lens, R0, HG, CNT + 0, 0);
  k_xg<<<256, 256, 0, stream>>>(R0, Wih, bih, bhh, XG, 1);
  k_lstm_mfma<<<16, 256, 0, stream>>>(XG, Whh, lens, R1, HG, CNT + 1, 1);
  k_attn_sc<<<256, 256, 0, stream>>>(R1, aW1, ab1, aw2, SC);
  k_ctx<<<64, 512, 0, stream>>>(SC, R1, lens, CTX);
  k_sample<<<4096, 256, 0, stream>>>(CTX, d2v, utab, atab, uids, sids,
                                     emW1, emb1, emW2, emb2, mlpW, mlpb,
                                     lmW1, lmb1, lmW2, lmb2, lmW3, lmb3,
                                     lmW4, lmb4, out);
}

// Round 3
// 2494.939 us; speedup vs baseline: 2.1319x; 1.4566x over previous
//
#include <hip/hip_runtime.h>
#include <cstddef>

namespace {

constexpr int T = 128;

typedef unsigned short u16;
typedef unsigned int u32;
typedef unsigned long long u64;
typedef __attribute__((ext_vector_type(8))) short short8;
typedef __attribute__((ext_vector_type(4))) float f32x4;

__device__ __forceinline__ u16 f2bf(float x) {
  u32 u = __float_as_uint(x);
  u = (u + 0x7FFFu + ((u >> 16) & 1u)) >> 16;
  return (u16)u;
}
__device__ __forceinline__ float bf2f(u16 v) {
  return __uint_as_float(((u32)v) << 16);
}
__device__ __forceinline__ float sigf(float x) {
  x = fminf(fmaxf(x, -30.f), 30.f);
  return 1.f / (1.f + __expf(-x));
}
__device__ __forceinline__ float tanhfast(float x) {
  float ax = fminf(fabsf(x), 15.f);
  float e = __expf(-2.f * ax);
  float t = (1.f - e) / (1.f + e);
  return x < 0.f ? -t : t;
}

// ---- WBF sub-offsets (ushort units) ----
constexpr int O_WIH = 0;            // 2*2048*512
constexpr int O_AW1 = 2097152;      // 512*512
constexpr int O_EM1 = 2359296;      // 128*128
constexpr int O_EM2 = 2375680;      // 64*128
constexpr int O_MLP = 2383872;      // 64*512
constexpr int O_LW1 = 2416640;      // 256*128
constexpr int O_LW2 = 2449408;      // 128*256
constexpr int O_LW3 = 2482176;      // 64*128
constexpr int N_WBF = 2490368;

// ---------------------------------------------------------------------------
// One-time fp32 -> bf16 weight conversion into workspace
// ---------------------------------------------------------------------------
__global__ __launch_bounds__(256)
void k_prep(const float* __restrict__ wih, const float* __restrict__ aw1,
            const float* __restrict__ e1, const float* __restrict__ e2,
            const float* __restrict__ mw, const float* __restrict__ l1,
            const float* __restrict__ l2, const float* __restrict__ l3,
            u16* __restrict__ wbf) {
  int i = blockIdx.x * 256 + threadIdx.x;
  if (i >= N_WBF) return;
  float v;
  if (i < O_AW1)      v = wih[i];
  else if (i < O_EM1) v = aw1[i - O_AW1];
  else if (i < O_EM2) v = e1[i - O_EM1];
  else if (i < O_MLP) v = e2[i - O_EM2];
  else if (i < O_LW1) v = mw[i - O_MLP];
  else if (i < O_LW2) v = l1[i - O_LW1];
  else if (i < O_LW3) v = l2[i - O_LW2];
  else                v = l3[i - O_LW3];
  wbf[i] = f2bf(v);
}

// ---------------------------------------------------------------------------
// xg = X @ Wih_l^T + bih + bhh   via MFMA.  grid (256 rowblk, 8 nchunk)
// ---------------------------------------------------------------------------
__global__ __launch_bounds__(256)
void k_xg_mfma(const float* __restrict__ X, const u16* __restrict__ Wbf,
               const float* __restrict__ bi, const float* __restrict__ bh,
               float* __restrict__ xg) {
  __shared__ __align__(16) u16 sx[32 * 520];
  int tid = threadIdx.x;
  int rowbase = blockIdx.x * 32;
  int nchunk = blockIdx.y;
  for (int idx = tid; idx < 4096; idx += 256) {
    int r = idx >> 7, k4 = idx & 127;
    float4 v = *(const float4*)(X + (size_t)(rowbase + r) * 512 + k4 * 4);
    u32* p = (u32*)(sx + r * 520 + k4 * 4);
    p[0] = (u32)f2bf(v.x) | ((u32)f2bf(v.y) << 16);
    p[1] = (u32)f2bf(v.z) | ((u32)f2bf(v.w) << 16);
  }
  __syncthreads();
  int w = tid >> 6, lane = tid & 63;
  int msub = w >> 1, nhalf = w & 1;
  int mbase = msub * 16;
  int nb0 = nchunk * 256 + nhalf * 128;
  f32x4 acc[8];
#pragma unroll
  for (int i = 0; i < 8; ++i) acc[i] = f32x4{0.f, 0.f, 0.f, 0.f};
  for (int kt = 0; kt < 16; ++kt) {
    short8 a = *(const short8*)(sx + (mbase + (lane & 15)) * 520 + kt * 32 + (lane >> 4) * 8);
#pragma unroll
    for (int nt = 0; nt < 8; ++nt) {
      short8 b = *(const short8*)(Wbf + (size_t)(nb0 + nt * 16 + (lane & 15)) * 512 +
                                  kt * 32 + (lane >> 4) * 8);
      acc[nt] = __builtin_amdgcn_mfma_f32_16x16x32_bf16(a, b, acc[nt], 0, 0, 0);
    }
  }
  int mr = mbase + (lane >> 4) * 4;
#pragma unroll
  for (int nt = 0; nt < 8; ++nt) {
    int n = nb0 + nt * 16 + (lane & 15);
    float bb = bi[n] + bh[n];
#pragma unroll
    for (int r = 0; r < 4; ++r)
      xg[(size_t)(rowbase + mr + r) * 2048 + n] = acc[nt][r] + bb;
  }
}

// ---------------------------------------------------------------------------
// MFMA LSTM: 16 blocks = [d:2][hidden chunk c:8]. Weights in registers.
// h exchanged via cache-bypassing agent-scope atomics; fence-free barrier.
// ---------------------------------------------------------------------------
__global__ __launch_bounds__(256, 1)
void k_lstm_mfma(const float* __restrict__ xg, const float* __restrict__ whh,
                 const int* __restrict__ lens, float* __restrict__ out,
                 u16* __restrict__ hg, unsigned* __restrict__ cnt, int layer) {
  const int d = blockIdx.x >> 3, c = blockIdx.x & 7;
  const int tid = threadIdx.x;
  const int w = tid >> 6, l = tid & 63;
  const int lrow = l & 15, lhi = l >> 4;

  short8 Bf[8][8];
  const float* wbase = whh + (size_t)(layer * 2 + d) * 262144;
#pragma unroll
  for (int kk = 0; kk < 8; ++kk) {
#pragma unroll
    for (int nt = 0; nt < 8; ++nt) {
      int g = nt >> 1;
      int nl = (nt & 1) * 16 + lrow;
      const float* rp = wbase + (size_t)(g * 256 + c * 32 + nl) * 256 + kk * 32 + lhi * 8;
      float4 lo = *(const float4*)rp;
      float4 hi = *(const float4*)(rp + 4);
      short8 b;
      b[0] = (short)f2bf(lo.x); b[1] = (short)f2bf(lo.y);
      b[2] = (short)f2bf(lo.z); b[3] = (short)f2bf(lo.w);
      b[4] = (short)f2bf(hi.x); b[5] = (short)f2bf(hi.y);
      b[6] = (short)f2bf(hi.z); b[7] = (short)f2bf(hi.w);
      Bf[kk][nt] = b;
    }
  }

  u16* h0buf = hg + ((d << 1) | 0) * 16384;   // [64 batch][256 j] bf16
  u16* h1buf = hg + ((d << 1) | 1) * 16384;

  const int mb = w * 16 + lhi * 4;
  int mlen[4];
#pragma unroll
  for (int r = 0; r < 4; ++r) mlen[r] = lens[mb + r];

  float cst[2][4], hst[2][4];
#pragma unroll
  for (int hx = 0; hx < 2; ++hx)
#pragma unroll
    for (int r = 0; r < 4; ++r) { cst[hx][r] = 0.f; hst[hx][r] = 0.f; }

  for (int s = 0; s < 128; ++s) {
    const int t = d ? (127 - s) : s;

    float xv[8][4];
#pragma unroll
    for (int nt = 0; nt < 8; ++nt) {
      int nglob = d * 1024 + (nt >> 1) * 256 + c * 32 + (nt & 1) * 16 + lrow;
#pragma unroll
      for (int r = 0; r < 4; ++r)
        xv[nt][r] = xg[((size_t)(mb + r) * 128 + t) * 2048 + nglob];
    }

    f32x4 acc[8];
#pragma unroll
    for (int nt = 0; nt < 8; ++nt) acc[nt] = f32x4{0.f, 0.f, 0.f, 0.f};

    if (s > 0) {
      const u16* hp = (s & 1) ? h1buf : h0buf;
#pragma unroll
      for (int kk = 0; kk < 8; ++kk) {
        u64* p = (u64*)(hp + (w * 16 + lrow) * 256 + kk * 32 + lhi * 8);
        union { u64 q[2]; short8 v; } ua;
        ua.q[0] = __hip_atomic_load(p, __ATOMIC_RELAXED, __HIP_MEMORY_SCOPE_AGENT);
        ua.q[1] = __hip_atomic_load(p + 1, __ATOMIC_RELAXED, __HIP_MEMORY_SCOPE_AGENT);
        short8 a = ua.v;
#pragma unroll
        for (int nt = 0; nt < 8; ++nt)
          acc[nt] = __builtin_amdgcn_mfma_f32_16x16x32_bf16(a, Bf[kk][nt], acc[nt], 0, 0, 0);
      }
    }

    u16* hw = (s & 1) ? h0buf : h1buf;   // write opposite parity
#pragma unroll
    for (int hx = 0; hx < 2; ++hx) {
#pragma unroll
      for (int r = 0; r < 4; ++r) {
        float gi = acc[0 + hx][r] + xv[0 + hx][r];
        float gf = acc[2 + hx][r] + xv[2 + hx][r];
        float gg = acc[4 + hx][r] + xv[4 + hx][r];
        float go = acc[6 + hx][r] + xv[6 + hx][r];
        float c2 = sigf(gf) * cst[hx][r] + sigf(gi) * tanhfast(gg);
        float h2 = sigf(go) * tanhfast(c2);
        bool upd = t < mlen[r];
        cst[hx][r] = upd ? c2 : cst[hx][r];
        float hn = upd ? h2 : hst[hx][r];
        hst[hx][r] = hn;
        int m = mb + r;
        int j = c * 32 + hx * 16 + lrow;
        out[((size_t)m * 128 + t) * 512 + d * 256 + j] = hn;
        // pack (j even, j odd) pair via lane exchange, store as one u32 atomic
        u16 myv = f2bf(hn);
        int other = __shfl_xor((int)myv, 1);
        u32 word = (lrow & 1) ? (((u32)myv << 16) | (u32)(u16)other)
                              : ((u32)myv | ((u32)(u16)other << 16));
        if (((r ^ lrow) & 1) == 0) {
          int jw = j & ~1;
          __hip_atomic_store((u32*)(hw + m * 256 + jw), word,
                             __ATOMIC_RELAXED, __HIP_MEMORY_SCOPE_AGENT);
        }
      }
    }

    if (s < 127) {
      __syncthreads();   // compiler drains vmcnt(0) before s_barrier: store-acks done
      if (tid == 0) {
        __hip_atomic_fetch_add(cnt, 1u, __ATOMIC_RELAXED, __HIP_MEMORY_SCOPE_AGENT);
        unsigned target = 16u * (unsigned)(s + 1);
        while (__hip_atomic_load(cnt, __ATOMIC_RELAXED, __HIP_MEMORY_SCOPE_AGENT) < target)
          __builtin_amdgcn_s_sleep(2);
      }
      __syncthreads();
    }
  }
}

// ---------------------------------------------------------------------------
// attn scores via MFMA: sc[m] = w2 . tanh(W1 @ rnn[m] + b1)
// ---------------------------------------------------------------------------
__global__ __launch_bounds__(256)
void k_attn(const float* __restrict__ rnn, const u16* __restrict__ W1bf,
            const float* __restrict__ b1, const float* __restrict__ w2,
            float* __restrict__ sc) {
  __shared__ __align__(16) u16 sx[32 * 520];
  __shared__ float sred[32];
  int tid = threadIdx.x;
  int rowbase = blockIdx.x * 32;
  for (int idx = tid; idx < 4096; idx += 256) {
    int r = idx >> 7, k4 = idx & 127;
    float4 v = *(const float4*)(rnn + (size_t)(rowbase + r) * 512 + k4 * 4);
    u32* p = (u32*)(sx + r * 520 + k4 * 4);
    p[0] = (u32)f2bf(v.x) | ((u32)f2bf(v.y) << 16);
    p[1] = (u32)f2bf(v.z) | ((u32)f2bf(v.w) << 16);
  }
  if (tid < 32) sred[tid] = 0.f;
  __syncthreads();
  int w = tid >> 6, lane = tid & 63;
  int msub = w >> 1, nhalf = w & 1;
  int mbase = msub * 16;
  float psum[4] = {0.f, 0.f, 0.f, 0.f};
  for (int ng = 0; ng < 4; ++ng) {
    f32x4 acc[4];
#pragma unroll
    for (int i = 0; i < 4; ++i) acc[i] = f32x4{0.f, 0.f, 0.f, 0.f};
    for (int kt = 0; kt < 16; ++kt) {
      short8 a = *(const short8*)(sx + (mbase + (lane & 15)) * 520 + kt * 32 + (lane >> 4) * 8);
#pragma unroll
      for (int nt = 0; nt < 4; ++nt) {
        int nrow = nhalf * 256 + ng * 64 + nt * 16 + (lane & 15);
        short8 b = *(const short8*)(W1bf + (size_t)nrow * 512 + kt * 32 + (lane >> 4) * 8);
        acc[nt] = __builtin_amdgcn_mfma_f32_16x16x32_bf16(a, b, acc[nt], 0, 0, 0);
      }
    }
#pragma unroll
    for (int nt = 0; nt < 4; ++nt) {
      int n = nhalf * 256 + ng * 64 + nt * 16 + (lane & 15);
      float wn = w2[n], bn = b1[n];
#pragma unroll
      for (int r = 0; r < 4; ++r) psum[r] += wn * tanhf(acc[nt][r] + bn);
    }
  }
#pragma unroll
  for (int off = 8; off >= 1; off >>= 1)
#pragma unroll
    for (int r = 0; r < 4; ++r) psum[r] += __shfl_xor(psum[r], off);
  if ((lane & 15) == 0) {
#pragma unroll
    for (int r = 0; r < 4; ++r)
      atomicAdd(&sred[msub * 16 + (lane >> 4) * 4 + r], psum[r]);
  }
  __syncthreads();
  if (tid < 32) sc[rowbase + tid] = sred[tid];
}

// ---------------------------------------------------------------------------
// Causal softmax + weighted sum as prefix scan
// ---------------------------------------------------------------------------
__global__ __launch_bounds__(512)
void k_ctx(const float* __restrict__ sc, const float* __restrict__ rnn,
           const int* __restrict__ lens, float* __restrict__ ctx) {
  int b = blockIdx.x;
  int h = threadIdx.x;
  __shared__ float ex[T];
  if (h < T) ex[h] = expf(sc[b * T + h]);
  __syncthreads();
  int len = lens[b];
  float acc = 0.f, den = 0.f;
  for (int t = 0; t < T; ++t) {
    float wv = ex[t];
    den += wv;
    acc += wv * rnn[((size_t)b * T + t) * 512 + h];
    ctx[((size_t)b * T + t) * 512 + h] = (t < len) ? (acc / den) : 0.f;
  }
}

// ---------------------------------------------------------------------------
// MFMA MLP stage on a 32-row bf16 LDS tile
// ---------------------------------------------------------------------------
template <int NT, int KT, bool RELU>
__device__ __forceinline__ void stage_mfma(const u16* __restrict__ Wbf,
                                           const float* __restrict__ bias,
                                           const u16* A, int lda,
                                           u16* O, int ldo, int nofs,
                                           int lane, int msub, int nhalf) {
  f32x4 acc[NT];
#pragma unroll
  for (int i = 0; i < NT; ++i) acc[i] = f32x4{0.f, 0.f, 0.f, 0.f};
  int mbase = msub * 16;
  int nb0 = nhalf * (NT * 16);
#pragma unroll
  for (int kt = 0; kt < KT; ++kt) {
    short8 a = *(const short8*)(A + (mbase + (lane & 15)) * lda + kt * 32 + (lane >> 4) * 8);
#pragma unroll
    for (int nt = 0; nt < NT; ++nt) {
      short8 b = *(const short8*)(Wbf + (size_t)(nb0 + nt * 16 + (lane & 15)) * (KT * 32) +
                                  kt * 32 + (lane >> 4) * 8);
      acc[nt] = __builtin_amdgcn_mfma_f32_16x16x32_bf16(a, b, acc[nt], 0, 0, 0);
    }
  }
  int mr = mbase + (lane >> 4) * 4;
#pragma unroll
  for (int nt = 0; nt < NT; ++nt) {
    int nl = nb0 + nt * 16 + (lane & 15);
    float bv = bias[nl];
#pragma unroll
    for (int r = 0; r < 4; ++r) {
      float v = acc[nt][r] + bv;
      if (RELU) v = fmaxf(v, 0.f);
      O[(mr + r) * ldo + nofs + nl] = f2bf(v);
    }
  }
}

// ---------------------------------------------------------------------------
// Fused sample branch, MFMA everywhere. 32 rows/block, 4096 blocks.
// ---------------------------------------------------------------------------
__global__ __launch_bounds__(256)
void k_sample(const float* __restrict__ ctx, const float* __restrict__ d2v,
              const float* __restrict__ user_table, const float* __restrict__ art_table,
              const int* __restrict__ user_ids, const int* __restrict__ sample_ids,
              const u16* __restrict__ wbf,
              const float* __restrict__ em_b1, const float* __restrict__ em_b2,
              const float* __restrict__ mlp_b,
              const float* __restrict__ lm_b1, const float* __restrict__ lm_b2,
              const float* __restrict__ lm_b3,
              const float* __restrict__ lm_W4, const float* __restrict__ lm_b4,
              float* __restrict__ out) {
  __shared__ __align__(16) u16 bufA[32 * 520];
  __shared__ __align__(16) u16 bufB[32 * 264];
  __shared__ __align__(16) u16 bufC[32 * 136];
  int tid = threadIdx.x, lane = tid & 63, w = tid >> 6;
  int msub = w >> 1, nhalf = w & 1;
  int rowbase = blockIdx.x * 32;

  // e0 = user_emb * art_emb  -> bufA[:, 0:128]
  for (int idx = tid; idx < 1024; idx += 256) {
    int r = idx >> 5, k4 = idx & 31;
    int m = rowbase + r;
    int sid = sample_ids[m];
    int uid = user_ids[m >> 11];
    float4 u = *(const float4*)(user_table + (size_t)uid * 128 + k4 * 4);
    float4 a = *(const float4*)(art_table + (size_t)sid * 128 + k4 * 4);
    u32* p = (u32*)(bufA + r * 520 + k4 * 4);
    p[0] = (u32)f2bf(u.x * a.x) | ((u32)f2bf(u.y * a.y) << 16);
    p[1] = (u32)f2bf(u.z * a.z) | ((u32)f2bf(u.w * a.w) << 16);
  }
  __syncthreads();
  stage_mfma<4, 4, true>(wbf + O_EM1, em_b1, bufA, 520, bufB, 264, 0, lane, msub, nhalf);
  __syncthreads();
  // em2 (reads bufB, writes bufC) + r-input staging (writes bufA) between same syncs
  stage_mfma<2, 4, true>(wbf + O_EM2, em_b2, bufB, 264, bufC, 136, 0, lane, msub, nhalf);
  for (int idx = tid; idx < 4096; idx += 256) {
    int r = idx >> 7, k4 = idx & 127;
    int m = rowbase + r;
    int bt = m >> 4;
    float4 cx = *(const float4*)(ctx + (size_t)bt * 512 + k4 * 4);
    float4 dv = *(const float4*)(d2v + (size_t)m * 512 + k4 * 4);
    u32* p = (u32*)(bufA + r * 520 + k4 * 4);
    p[0] = (u32)f2bf(cx.x * dv.x) | ((u32)f2bf(cx.y * dv.y) << 16);
    p[1] = (u32)f2bf(cx.z * dv.z) | ((u32)f2bf(cx.w * dv.w) << 16);
  }
  __syncthreads();
  stage_mfma<2, 16, false>(wbf + O_MLP, mlp_b, bufA, 520, bufC, 136, 64, lane, msub, nhalf);
  __syncthreads();
  stage_mfma<8, 4, true>(wbf + O_LW1, lm_b1, bufC, 136, bufB, 264, 0, lane, msub, nhalf);
  __syncthreads();
  stage_mfma<4, 8, true>(wbf + O_LW2, lm_b2, bufB, 264, bufA, 520, 0, lane, msub, nhalf);
  __syncthreads();
  stage_mfma<2, 4, true>(wbf + O_LW3, lm_b3, bufA, 520, bufC, 136, 0, lane, msub, nhalf);
  __syncthreads();

  if (tid < 32) {
    float acc = lm_b4[0];
#pragma unroll
    for (int k = 0; k < 64; ++k) acc += bf2f(bufC[tid * 136 + k]) * lm_W4[k];
    out[rowbase + tid] = 1.f / (1.f + expf(-acc));
  }
}

}  // namespace

extern "C" void kernel_launch(void* const* d_in, const int* in_sizes, int n_in,
                              void* d_out, int out_size, void* d_ws, size_t ws_size,
                              hipStream_t stream) {
  const float* x1   = (const float*)d_in[0];
  const float* d2v  = (const float*)d_in[1];
  const float* Wih  = (const float*)d_in[2];
  const float* Whh  = (const float*)d_in[3];
  const float* bih  = (const float*)d_in[4];
  const float* bhh  = (const float*)d_in[5];
  const float* aW1  = (const float*)d_in[6];
  const float* ab1  = (const float*)d_in[7];
  const float* aw2  = (const float*)d_in[8];
  const float* mlpW = (const float*)d_in[9];
  const float* mlpb = (const float*)d_in[10];
  const float* utab = (const float*)d_in[11];
  const float* atab = (const float*)d_in[12];
  const float* emW1 = (const float*)d_in[13];
  const float* emb1 = (const float*)d_in[14];
  const float* emW2 = (const float*)d_in[15];
  const float* emb2 = (const float*)d_in[16];
  const float* lmW1 = (const float*)d_in[17];
  const float* lmb1 = (const float*)d_in[18];
  const float* lmW2 = (const float*)d_in[19];
  const float* lmb2 = (const float*)d_in[20];
  const float* lmW3 = (const float*)d_in[21];
  const float* lmb3 = (const float*)d_in[22];
  const float* lmW4 = (const float*)d_in[23];
  const float* lmb4 = (const float*)d_in[24];
  const int* lens   = (const int*)d_in[27];
  const int* uids   = (const int*)d_in[28];
  const int* sids   = (const int*)d_in[29];
  float* out = (float*)d_out;

  float* ws = (float*)d_ws;
  // float-offsets
  unsigned* CNT = (unsigned*)ws;                       // [0,16)
  u16* HG  = (u16*)(ws + 16);                          // 65536 ush = 32768 f
  float* SC  = ws + 32784;                             // 8192
  u16* WBF = (u16*)(ws + 40976);                       // 2,490,368 ush
  float* XG  = ws + 1286160;                           // 16,777,216
  float* R0  = ws + 18063376;                          // 4,194,304
  float* R1  = ws + 22257680;                          // 4,194,304
  float* CTX = ws + 26451984;                          // 4,194,304

  hipMemsetAsync(CNT, 0, 8, stream);
  k_prep<<<(N_WBF + 255) / 256, 256, 0, stream>>>(Wih, aW1, emW1, emW2, mlpW,
                                                  lmW1, lmW2, lmW3, WBF);
  k_xg_mfma<<<dim3(256, 8), 256, 0, stream>>>(x1, WBF + O_WIH, bih, bhh, XG);
  k_lstm_mfma<<<16, 256, 0, stream>>>(XG, Whh, lens, R0, HG, CNT + 0, 0);
  k_xg_mfma<<<dim3(256, 8), 256, 0, stream>>>(R0, WBF + O_WIH + 1048576,
                                              bih + 2048, bhh + 2048, XG);
  k_lstm_mfma<<<16, 256, 0, stream>>>(XG, Whh, lens, R1, HG, CNT + 1, 1);
  k_attn<<<256, 256, 0, stream>>>(R1, WBF + O_AW1, ab1, aw2, SC);
  k_ctx<<<64, 512, 0, stream>>>(SC, R1, lens, CTX);
  k_sample<<<4096, 256, 0, stream>>>(CTX, d2v, utab, atab, uids, sids, WBF,
                                     emb1, emb2, mlpb, lmb1, lmb2, lmb3,
                                     lmW4, lmb4, out);
}

// Round 4
// 1695.259 us; speedup vs baseline: 3.1376x; 1.4717x over previous
//
#include <hip/hip_runtime.h>
#include <cstddef>

namespace {

constexpr int T = 128;

typedef unsigned short u16;
typedef unsigned int u32;
typedef unsigned long long u64;
typedef __attribute__((ext_vector_type(8))) short short8;
typedef __attribute__((ext_vector_type(4))) float f32x4;

__device__ __forceinline__ u16 f2bf(float x) {
  u32 u = __float_as_uint(x);
  u = (u + 0x7FFFu + ((u >> 16) & 1u)) >> 16;
  return (u16)u;
}
__device__ __forceinline__ float bf2f(u16 v) {
  return __uint_as_float(((u32)v) << 16);
}
__device__ __forceinline__ float sigf(float x) {
  x = fminf(fmaxf(x, -30.f), 30.f);
  return 1.f / (1.f + __expf(-x));
}
__device__ __forceinline__ float tanhfast(float x) {
  float ax = fminf(fabsf(x), 15.f);
  float e = __expf(-2.f * ax);
  float t = (1.f - e) / (1.f + e);
  return x < 0.f ? -t : t;
}

// ---- WBF sub-offsets (ushort units) ----
constexpr int O_WIH = 0;            // 2*2048*512
constexpr int O_AW1 = 2097152;      // 512*512
constexpr int O_EM1 = 2359296;      // 128*128
constexpr int O_EM2 = 2375680;      // 64*128
constexpr int O_MLP = 2383872;      // 64*512
constexpr int O_LW1 = 2416640;      // 256*128
constexpr int O_LW2 = 2449408;      // 128*256
constexpr int O_LW3 = 2482176;      // 64*128
constexpr int N_WBF = 2490368;

// ---------------------------------------------------------------------------
// One-time fp32 -> bf16 weight conversion into workspace
// ---------------------------------------------------------------------------
__global__ __launch_bounds__(256)
void k_prep(const float* __restrict__ wih, const float* __restrict__ aw1,
            const float* __restrict__ e1, const float* __restrict__ e2,
            const float* __restrict__ mw, const float* __restrict__ l1,
            const float* __restrict__ l2, const float* __restrict__ l3,
            u16* __restrict__ wbf) {
  int i = blockIdx.x * 256 + threadIdx.x;
  if (i >= N_WBF) return;
  float v;
  if (i < O_AW1)      v = wih[i];
  else if (i < O_EM1) v = aw1[i - O_AW1];
  else if (i < O_EM2) v = e1[i - O_EM1];
  else if (i < O_MLP) v = e2[i - O_EM2];
  else if (i < O_LW1) v = mw[i - O_MLP];
  else if (i < O_LW2) v = l1[i - O_LW1];
  else if (i < O_LW3) v = l2[i - O_LW2];
  else                v = l3[i - O_LW3];
  wbf[i] = f2bf(v);
}

// ---------------------------------------------------------------------------
// xg = X @ Wih_l^T + bih + bhh   via MFMA.  grid (256 rowblk, 8 nchunk)
// ---------------------------------------------------------------------------
__global__ __launch_bounds__(256)
void k_xg_mfma(const float* __restrict__ X, const u16* __restrict__ Wbf,
               const float* __restrict__ bi, const float* __restrict__ bh,
               float* __restrict__ xg) {
  __shared__ __align__(16) u16 sx[32 * 520];
  int tid = threadIdx.x;
  int rowbase = blockIdx.x * 32;
  int nchunk = blockIdx.y;
  for (int idx = tid; idx < 4096; idx += 256) {
    int r = idx >> 7, k4 = idx & 127;
    float4 v = *(const float4*)(X + (size_t)(rowbase + r) * 512 + k4 * 4);
    u32* p = (u32*)(sx + r * 520 + k4 * 4);
    p[0] = (u32)f2bf(v.x) | ((u32)f2bf(v.y) << 16);
    p[1] = (u32)f2bf(v.z) | ((u32)f2bf(v.w) << 16);
  }
  __syncthreads();
  int w = tid >> 6, lane = tid & 63;
  int msub = w >> 1, nhalf = w & 1;
  int mbase = msub * 16;
  int nb0 = nchunk * 256 + nhalf * 128;
  f32x4 acc[8];
#pragma unroll
  for (int i = 0; i < 8; ++i) acc[i] = f32x4{0.f, 0.f, 0.f, 0.f};
  for (int kt = 0; kt < 16; ++kt) {
    short8 a = *(const short8*)(sx + (mbase + (lane & 15)) * 520 + kt * 32 + (lane >> 4) * 8);
#pragma unroll
    for (int nt = 0; nt < 8; ++nt) {
      short8 b = *(const short8*)(Wbf + (size_t)(nb0 + nt * 16 + (lane & 15)) * 512 +
                                  kt * 32 + (lane >> 4) * 8);
      acc[nt] = __builtin_amdgcn_mfma_f32_16x16x32_bf16(a, b, acc[nt], 0, 0, 0);
    }
  }
  int mr = mbase + (lane >> 4) * 4;
#pragma unroll
  for (int nt = 0; nt < 8; ++nt) {
    int n = nb0 + nt * 16 + (lane & 15);
    float bb = bi[n] + bh[n];
#pragma unroll
    for (int r = 0; r < 4; ++r)
      xg[(size_t)(rowbase + mr + r) * 2048 + n] = acc[nt][r] + bb;
  }
}

// ---------------------------------------------------------------------------
// MFMA LSTM v2: 32 blocks = [d:2][j-chunk c:16 of 16 cols]. 128 weight VGPRs
// (no spill). Distributed write-once flags at LLC; consumer polls with 16
// lanes + ballot, no consumer-side barrier. h exchanged via agent-scope
// atomics (cache-bypass, ping-pong parity buffers).
// ---------------------------------------------------------------------------
__global__ __launch_bounds__(256, 1)
void k_lstm2(const float* __restrict__ xg, const float* __restrict__ whh,
             const int* __restrict__ lens, float* __restrict__ out,
             u16* __restrict__ hg, u32* __restrict__ flg, int layer) {
  const int d = blockIdx.x >> 4, c = blockIdx.x & 15;
  const int tid = threadIdx.x;
  const int l = tid & 63;
  const int w = tid >> 6;
  const int ln = l & 15, lk = l >> 4;

  // B fragments: gate rows g*256 + c*16 + ln, k = kk*32 + lk*8 .. +8
  short8 Bf[8][4];
  const float* wbase = whh + (size_t)(layer * 2 + d) * 262144;
#pragma unroll
  for (int kk = 0; kk < 8; ++kk) {
#pragma unroll
    for (int g = 0; g < 4; ++g) {
      const float* rp = wbase + (size_t)(g * 256 + c * 16 + ln) * 256 + kk * 32 + lk * 8;
      float4 lo = *(const float4*)rp;
      float4 hi = *(const float4*)(rp + 4);
      short8 b;
      b[0] = (short)f2bf(lo.x); b[1] = (short)f2bf(lo.y);
      b[2] = (short)f2bf(lo.z); b[3] = (short)f2bf(lo.w);
      b[4] = (short)f2bf(hi.x); b[5] = (short)f2bf(hi.y);
      b[6] = (short)f2bf(hi.z); b[7] = (short)f2bf(hi.w);
      Bf[kk][g] = b;
    }
  }

  u16* hbuf0 = hg + d * 32768;          // parity 0: [64 m][256 j] bf16
  u16* hbuf1 = hbuf0 + 16384;           // parity 1
  u32* myflg = flg + (size_t)(layer * 2 + d) * 2048;   // [128 steps][16 blocks]

  const int m0 = w * 16;                // wave's batch tile base
  const int j  = c * 16 + ln;           // this lane's hidden col
  int mlen[4];
#pragma unroll
  for (int r = 0; r < 4; ++r) mlen[r] = lens[m0 + lk * 4 + r];

  float cst[4], hst[4];
#pragma unroll
  for (int r = 0; r < 4; ++r) { cst[r] = 0.f; hst[r] = 0.f; }

  // prefetch xv for s = 0
  float xv[4][4];
  {
    int t0 = d ? 127 : 0;
#pragma unroll
    for (int g = 0; g < 4; ++g)
#pragma unroll
      for (int r = 0; r < 4; ++r)
        xv[g][r] = xg[((size_t)(m0 + lk * 4 + r) * 128 + t0) * 2048 + d * 1024 + g * 256 + j];
  }

  for (int s = 0; s < 128; ++s) {
    const int t = d ? (127 - s) : s;

    f32x4 acc[4];
#pragma unroll
    for (int g = 0; g < 4; ++g) acc[g] = f32x4{0.f, 0.f, 0.f, 0.f};

    if (s > 0) {
      // ---- every wave polls the 16 producer flags of step s-1 ----
      const u32* fp = myflg + (size_t)(s - 1) * 16;
      for (;;) {
        u32 fv = (l < 16)
                     ? __hip_atomic_load(fp + l, __ATOMIC_RELAXED, __HIP_MEMORY_SCOPE_AGENT)
                     : 1u;
        if (__all(fv != 0)) break;
        __builtin_amdgcn_s_sleep(1);
      }
      // ---- A fragments: h_{s-1} from parity (s-1)&1, LLC reads ----
      const u16* hp = ((s - 1) & 1) ? hbuf1 : hbuf0;
#pragma unroll
      for (int kk = 0; kk < 8; ++kk) {
        const u64* p = (const u64*)(hp + (m0 + ln) * 256 + kk * 32 + lk * 8);
        union { u64 q[2]; short8 v; } ua;
        ua.q[0] = __hip_atomic_load(p, __ATOMIC_RELAXED, __HIP_MEMORY_SCOPE_AGENT);
        ua.q[1] = __hip_atomic_load(p + 1, __ATOMIC_RELAXED, __HIP_MEMORY_SCOPE_AGENT);
        short8 a = ua.v;
#pragma unroll
        for (int g = 0; g < 4; ++g)
          acc[g] = __builtin_amdgcn_mfma_f32_16x16x32_bf16(a, Bf[kk][g], acc[g], 0, 0, 0);
      }
    }

    // ---- elementwise gates + state update; publish h_s to parity s&1 ----
    u16* hw = (s & 1) ? hbuf1 : hbuf0;
#pragma unroll
    for (int r = 0; r < 4; ++r) {
      float gi = acc[0][r] + xv[0][r];
      float gf = acc[1][r] + xv[1][r];
      float gg = acc[2][r] + xv[2][r];
      float go = acc[3][r] + xv[3][r];
      float c2 = sigf(gf) * cst[r] + sigf(gi) * tanhfast(gg);
      float h2 = sigf(go) * tanhfast(c2);
      const int m = m0 + lk * 4 + r;
      bool upd = t < mlen[r];
      cst[r] = upd ? c2 : cst[r];
      float hn = upd ? h2 : hst[r];
      hst[r] = hn;
      out[((size_t)m * 128 + t) * 512 + d * 256 + j] = hn;
      u16 myv = f2bf(hn);
      u16 other = (u16)__shfl_xor((int)myv, 1);
      u32 word = (ln & 1) ? (((u32)myv << 16) | (u32)other)
                          : ((u32)myv | ((u32)other << 16));
      if ((ln & 1) == 0)
        __hip_atomic_store((u32*)(hw + m * 256 + (j & ~1)), word,
                           __ATOMIC_RELAXED, __HIP_MEMORY_SCOPE_AGENT);
    }

    __syncthreads();   // drains vmcnt: all waves' h stores acked at LLC
    if (s < 127) {
      if (tid == 0)
        __hip_atomic_store(myflg + (size_t)s * 16 + c, 1u,
                           __ATOMIC_RELAXED, __HIP_MEMORY_SCOPE_AGENT);
      // prefetch xv for next step; flies during next poll
      const int tn = d ? (127 - (s + 1)) : (s + 1);
#pragma unroll
      for (int g = 0; g < 4; ++g)
#pragma unroll
        for (int r = 0; r < 4; ++r)
          xv[g][r] = xg[((size_t)(m0 + lk * 4 + r) * 128 + tn) * 2048 + d * 1024 + g * 256 + j];
    }
  }
}

// ---------------------------------------------------------------------------
// attn scores via MFMA: sc[m] = w2 . tanh(W1 @ rnn[m] + b1)
// ---------------------------------------------------------------------------
__global__ __launch_bounds__(256)
void k_attn(const float* __restrict__ rnn, const u16* __restrict__ W1bf,
            const float* __restrict__ b1, const float* __restrict__ w2,
            float* __restrict__ sc) {
  __shared__ __align__(16) u16 sx[32 * 520];
  __shared__ float sred[32];
  int tid = threadIdx.x;
  int rowbase = blockIdx.x * 32;
  for (int idx = tid; idx < 4096; idx += 256) {
    int r = idx >> 7, k4 = idx & 127;
    float4 v = *(const float4*)(rnn + (size_t)(rowbase + r) * 512 + k4 * 4);
    u32* p = (u32*)(sx + r * 520 + k4 * 4);
    p[0] = (u32)f2bf(v.x) | ((u32)f2bf(v.y) << 16);
    p[1] = (u32)f2bf(v.z) | ((u32)f2bf(v.w) << 16);
  }
  if (tid < 32) sred[tid] = 0.f;
  __syncthreads();
  int w = tid >> 6, lane = tid & 63;
  int msub = w >> 1, nhalf = w & 1;
  int mbase = msub * 16;
  float psum[4] = {0.f, 0.f, 0.f, 0.f};
  for (int ng = 0; ng < 4; ++ng) {
    f32x4 acc[4];
#pragma unroll
    for (int i = 0; i < 4; ++i) acc[i] = f32x4{0.f, 0.f, 0.f, 0.f};
    for (int kt = 0; kt < 16; ++kt) {
      short8 a = *(const short8*)(sx + (mbase + (lane & 15)) * 520 + kt * 32 + (lane >> 4) * 8);
#pragma unroll
      for (int nt = 0; nt < 4; ++nt) {
        int nrow = nhalf * 256 + ng * 64 + nt * 16 + (lane & 15);
        short8 b = *(const short8*)(W1bf + (size_t)nrow * 512 + kt * 32 + (lane >> 4) * 8);
        acc[nt] = __builtin_amdgcn_mfma_f32_16x16x32_bf16(a, b, acc[nt], 0, 0, 0);
      }
    }
#pragma unroll
    for (int nt = 0; nt < 4; ++nt) {
      int n = nhalf * 256 + ng * 64 + nt * 16 + (lane & 15);
      float wn = w2[n], bn = b1[n];
#pragma unroll
      for (int r = 0; r < 4; ++r) psum[r] += wn * tanhf(acc[nt][r] + bn);
    }
  }
#pragma unroll
  for (int off = 8; off >= 1; off >>= 1)
#pragma unroll
    for (int r = 0; r < 4; ++r) psum[r] += __shfl_xor(psum[r], off);
  if ((lane & 15) == 0) {
#pragma unroll
    for (int r = 0; r < 4; ++r)
      atomicAdd(&sred[msub * 16 + (lane >> 4) * 4 + r], psum[r]);
  }
  __syncthreads();
  if (tid < 32) sc[rowbase + tid] = sred[tid];
}

// ---------------------------------------------------------------------------
// Causal softmax + weighted sum as prefix scan
// ---------------------------------------------------------------------------
__global__ __launch_bounds__(512)
void k_ctx(const float* __restrict__ sc, const float* __restrict__ rnn,
           const int* __restrict__ lens, float* __restrict__ ctx) {
  int b = blockIdx.x;
  int h = threadIdx.x;
  __shared__ float ex[T];
  if (h < T) ex[h] = expf(sc[b * T + h]);
  __syncthreads();
  int len = lens[b];
  float acc = 0.f, den = 0.f;
  for (int t = 0; t < T; ++t) {
    float wv = ex[t];
    den += wv;
    acc += wv * rnn[((size_t)b * T + t) * 512 + h];
    ctx[((size_t)b * T + t) * 512 + h] = (t < len) ? (acc / den) : 0.f;
  }
}

// ---------------------------------------------------------------------------
// MFMA MLP stage on a 32-row bf16 LDS tile
// ---------------------------------------------------------------------------
template <int NT, int KT, bool RELU>
__device__ __forceinline__ void stage_mfma(const u16* __restrict__ Wbf,
                                           const float* __restrict__ bias,
                                           const u16* A, int lda,
                                           u16* O, int ldo, int nofs,
                                           int lane, int msub, int nhalf) {
  f32x4 acc[NT];
#pragma unroll
  for (int i = 0; i < NT; ++i) acc[i] = f32x4{0.f, 0.f, 0.f, 0.f};
  int mbase = msub * 16;
  int nb0 = nhalf * (NT * 16);
#pragma unroll
  for (int kt = 0; kt < KT; ++kt) {
    short8 a = *(const short8*)(A + (mbase + (lane & 15)) * lda + kt * 32 + (lane >> 4) * 8);
#pragma unroll
    for (int nt = 0; nt < NT; ++nt) {
      short8 b = *(const short8*)(Wbf + (size_t)(nb0 + nt * 16 + (lane & 15)) * (KT * 32) +
                                  kt * 32 + (lane >> 4) * 8);
      acc[nt] = __builtin_amdgcn_mfma_f32_16x16x32_bf16(a, b, acc[nt], 0, 0, 0);
    }
  }
  int mr = mbase + (lane >> 4) * 4;
#pragma unroll
  for (int nt = 0; nt < NT; ++nt) {
    int nl = nb0 + nt * 16 + (lane & 15);
    float bv = bias[nl];
#pragma unroll
    for (int r = 0; r < 4; ++r) {
      float v = acc[nt][r] + bv;
      if (RELU) v = fmaxf(v, 0.f);
      O[(mr + r) * ldo + nofs + nl] = f2bf(v);
    }
  }
}

// ---------------------------------------------------------------------------
// Fused sample branch, MFMA everywhere. 32 rows/block, 4096 blocks.
// ---------------------------------------------------------------------------
__global__ __launch_bounds__(256)
void k_sample(const float* __restrict__ ctx, const float* __restrict__ d2v,
              const float* __restrict__ user_table, const float* __restrict__ art_table,
              const int* __restrict__ user_ids, const int* __restrict__ sample_ids,
              const u16* __restrict__ wbf,
              const float* __restrict__ em_b1, const float* __restrict__ em_b2,
              const float* __restrict__ mlp_b,
              const float* __restrict__ lm_b1, const float* __restrict__ lm_b2,
              const float* __restrict__ lm_b3,
              const float* __restrict__ lm_W4, const float* __restrict__ lm_b4,
              float* __restrict__ out) {
  __shared__ __align__(16) u16 bufA[32 * 520];
  __shared__ __align__(16) u16 bufB[32 * 264];
  __shared__ __align__(16) u16 bufC[32 * 136];
  int tid = threadIdx.x, lane = tid & 63, w = tid >> 6;
  int msub = w >> 1, nhalf = w & 1;
  int rowbase = blockIdx.x * 32;

  for (int idx = tid; idx < 1024; idx += 256) {
    int r = idx >> 5, k4 = idx & 31;
    int m = rowbase + r;
    int sid = sample_ids[m];
    int uid = user_ids[m >> 11];
    float4 u = *(const float4*)(user_table + (size_t)uid * 128 + k4 * 4);
    float4 a = *(const float4*)(art_table + (size_t)sid * 128 + k4 * 4);
    u32* p = (u32*)(bufA + r * 520 + k4 * 4);
    p[0] = (u32)f2bf(u.x * a.x) | ((u32)f2bf(u.y * a.y) << 16);
    p[1] = (u32)f2bf(u.z * a.z) | ((u32)f2bf(u.w * a.w) << 16);
  }
  __syncthreads();
  stage_mfma<4, 4, true>(wbf + O_EM1, em_b1, bufA, 520, bufB, 264, 0, lane, msub, nhalf);
  __syncthreads();
  stage_mfma<2, 4, true>(wbf + O_EM2, em_b2, bufB, 264, bufC, 136, 0, lane, msub, nhalf);
  for (int idx = tid; idx < 4096; idx += 256) {
    int r = idx >> 7, k4 = idx & 127;
    int m = rowbase + r;
    int bt = m >> 4;
    float4 cx = *(const float4*)(ctx + (size_t)bt * 512 + k4 * 4);
    float4 dv = *(const float4*)(d2v + (size_t)m * 512 + k4 * 4);
    u32* p = (u32*)(bufA + r * 520 + k4 * 4);
    p[0] = (u32)f2bf(cx.x * dv.x) | ((u32)f2bf(cx.y * dv.y) << 16);
    p[1] = (u32)f2bf(cx.z * dv.z) | ((u32)f2bf(cx.w * dv.w) << 16);
  }
  __syncthreads();
  stage_mfma<2, 16, false>(wbf + O_MLP, mlp_b, bufA, 520, bufC, 136, 64, lane, msub, nhalf);
  __syncthreads();
  stage_mfma<8, 4, true>(wbf + O_LW1, lm_b1, bufC, 136, bufB, 264, 0, lane, msub, nhalf);
  __syncthreads();
  stage_mfma<4, 8, true>(wbf + O_LW2, lm_b2, bufB, 264, bufA, 520, 0, lane, msub, nhalf);
  __syncthreads();
  stage_mfma<2, 4, true>(wbf + O_LW3, lm_b3, bufA, 520, bufC, 136, 0, lane, msub, nhalf);
  __syncthreads();

  if (tid < 32) {
    float acc = lm_b4[0];
#pragma unroll
    for (int k = 0; k < 64; ++k) acc += bf2f(bufC[tid * 136 + k]) * lm_W4[k];
    out[rowbase + tid] = 1.f / (1.f + expf(-acc));
  }
}

}  // namespace

extern "C" void kernel_launch(void* const* d_in, const int* in_sizes, int n_in,
                              void* d_out, int out_size, void* d_ws, size_t ws_size,
                              hipStream_t stream) {
  const float* x1   = (const float*)d_in[0];
  const float* d2v  = (const float*)d_in[1];
  const float* Wih  = (const float*)d_in[2];
  const float* Whh  = (const float*)d_in[3];
  const float* bih  = (const float*)d_in[4];
  const float* bhh  = (const float*)d_in[5];
  const float* aW1  = (const float*)d_in[6];
  const float* ab1  = (const float*)d_in[7];
  const float* aw2  = (const float*)d_in[8];
  const float* mlpW = (const float*)d_in[9];
  const float* mlpb = (const float*)d_in[10];
  const float* utab = (const float*)d_in[11];
  const float* atab = (const float*)d_in[12];
  const float* emW1 = (const float*)d_in[13];
  const float* emb1 = (const float*)d_in[14];
  const float* emW2 = (const float*)d_in[15];
  const float* emb2 = (const float*)d_in[16];
  const float* lmW1 = (const float*)d_in[17];
  const float* lmb1 = (const float*)d_in[18];
  const float* lmW2 = (const float*)d_in[19];
  const float* lmb2 = (const float*)d_in[20];
  const float* lmW3 = (const float*)d_in[21];
  const float* lmb3 = (const float*)d_in[22];
  const float* lmW4 = (const float*)d_in[23];
  const float* lmb4 = (const float*)d_in[24];
  const int* lens   = (const int*)d_in[27];
  const int* uids   = (const int*)d_in[28];
  const int* sids   = (const int*)d_in[29];
  float* out = (float*)d_out;

  float* ws = (float*)d_ws;
  // float-unit offsets
  u32* FLG = (u32*)ws;                                 // 8192 u32  [0, 8192)
  u16* HG  = (u16*)(ws + 8192);                        // 65536 u16 [8192, 40960)
  float* SC  = ws + 40960;                             // 8192      [40960, 49152)
  u16* WBF = (u16*)(ws + 49152);                       // 2,490,368 u16
  float* XG  = ws + 1294336;                           // 16,777,216
  float* R0  = ws + 18071552;                          // 4,194,304
  float* R1  = ws + 22265856;                          // 4,194,304
  float* CTX = ws + 26460160;                          // 4,194,304

  hipMemsetAsync(FLG, 0, 32768, stream);
  k_prep<<<(N_WBF + 255) / 256, 256, 0, stream>>>(Wih, aW1, emW1, emW2, mlpW,
                                                  lmW1, lmW2, lmW3, WBF);
  k_xg_mfma<<<dim3(256, 8), 256, 0, stream>>>(x1, WBF + O_WIH, bih, bhh, XG);
  k_lstm2<<<32, 256, 0, stream>>>(XG, Whh, lens, R0, HG, FLG, 0);
  k_xg_mfma<<<dim3(256, 8), 256, 0, stream>>>(R0, WBF + O_WIH + 1048576,
                                              bih + 2048, bhh + 2048, XG);
  k_lstm2<<<32, 256, 0, stream>>>(XG, Whh, lens, R1, HG, FLG, 1);
  k_attn<<<256, 256, 0, stream>>>(R1, WBF + O_AW1, ab1, aw2, SC);
  k_ctx<<<64, 512, 0, stream>>>(SC, R1, lens, CTX);
  k_sample<<<4096, 256, 0, stream>>>(CTX, d2v, utab, atab, uids, sids, WBF,
                                     emb1, emb2, mlpb, lmb1, lmb2, lmb3,
                                     lmW4, lmb4, out);
}